// Round 1
// baseline (688.155 us; speedup 1.0000x reference)
//
#include <hip/hip_runtime.h>
#include <stdint.h>

typedef float v4f __attribute__((ext_vector_type(4)));
typedef short v8s __attribute__((ext_vector_type(8)));

#define SZ_BHTD 8388608   // B*H*T*DH
#define SZ_HTD  131072    // T*DH

__device__ __forceinline__ uint16_t f2bf(float f){
  uint32_t u = __float_as_uint(f);
  u += 0x7fffu + ((u >> 16) & 1u);
  return (uint16_t)(u >> 16);
}
__device__ __forceinline__ float bf2f(uint16_t v){
  return __uint_as_float(((uint32_t)v) << 16);
}

// x fp32 -> bf16 (4 elems/thread)
__global__ __launch_bounds__(256) void k_conv_x(const float* __restrict__ x, uint16_t* __restrict__ xb){
  int i = blockIdx.x*256 + threadIdx.x;
  const float4 v = ((const float4*)x)[i];
  ushort4 o; o.x = f2bf(v.x); o.y = f2bf(v.y); o.z = f2bf(v.z); o.w = f2bf(v.w);
  ((ushort4*)xb)[i] = o;
}

// Wq/Wk/Wv fp32 [1024][1024] -> Wt bf16 [3072][1024], Wt[n][k] = W[k][n]
__global__ __launch_bounds__(256) void k_conv_w(const float* __restrict__ Wq, const float* __restrict__ Wk,
                                                const float* __restrict__ Wv, uint16_t* __restrict__ wt){
  __shared__ float t[64][65];
  const float* W = blockIdx.z==0 ? Wq : (blockIdx.z==1 ? Wk : Wv);
  int n0 = blockIdx.x*64, k0 = blockIdx.y*64;
  for (int idx = threadIdx.x; idx < 4096; idx += 256){
    int r = idx >> 6, c = idx & 63;
    t[r][c] = W[(k0+r)*1024 + n0 + c];
  }
  __syncthreads();
  for (int idx = threadIdx.x; idx < 4096; idx += 256){
    int r = idx >> 6, c = idx & 63;   // r: local n, c: local k
    wt[(size_t)(blockIdx.z*1024 + n0 + r)*1024 + k0 + c] = f2bf(t[c][r]);
  }
}

// QKV = Xb @ W (B-operand given transposed). Out bf16 [3][B][H][T][DH].
__global__ __launch_bounds__(256) void k_gemm(const uint16_t* __restrict__ Xb, const uint16_t* __restrict__ Wt,
                                              uint16_t* __restrict__ qkv){
  __shared__ uint16_t As[64*72];
  __shared__ uint16_t Bs[64*72];
  const int tid = threadIdx.x;
  const int lane = tid & 63, w = tid >> 6;
  const int quad = lane >> 4, l16 = lane & 15;
  const int bm = blockIdx.x, bn = blockIdx.y;
  v4f acc[4] = {{0,0,0,0},{0,0,0,0},{0,0,0,0},{0,0,0,0}};
  const int rowA = tid >> 3, col8 = (tid & 7)*8;
  const uint16_t* xa = Xb + (size_t)(bm*64)*1024;
  const uint16_t* wb = Wt + (size_t)(bn*64)*1024;
  for (int k0 = 0; k0 < 1024; k0 += 64){
    *(uint4*)&As[rowA*72 + col8]      = *(const uint4*)&xa[(size_t)rowA*1024 + k0 + col8];
    *(uint4*)&As[(rowA+32)*72 + col8] = *(const uint4*)&xa[(size_t)(rowA+32)*1024 + k0 + col8];
    *(uint4*)&Bs[rowA*72 + col8]      = *(const uint4*)&wb[(size_t)rowA*1024 + k0 + col8];
    *(uint4*)&Bs[(rowA+32)*72 + col8] = *(const uint4*)&wb[(size_t)(rowA+32)*1024 + k0 + col8];
    __syncthreads();
    #pragma unroll
    for (int kk = 0; kk < 64; kk += 32){
      v8s a = *(v8s*)&As[(w*16 + l16)*72 + kk + quad*8];
      #pragma unroll
      for (int ns = 0; ns < 4; ++ns){
        v8s b = *(v8s*)&Bs[(ns*16 + l16)*72 + kk + quad*8];
        acc[ns] = __builtin_amdgcn_mfma_f32_16x16x32_bf16(a, b, acc[ns], 0, 0, 0);
      }
    }
    __syncthreads();
  }
  #pragma unroll
  for (int ns = 0; ns < 4; ++ns){
    int n = bn*64 + ns*16 + l16;
    int which = n >> 10, cch = n & 1023;
    int h = cch >> 6, d = cch & 63;
    #pragma unroll
    for (int r = 0; r < 4; ++r){
      int m = bm*64 + w*16 + quad*4 + r;
      int b = m >> 11, t = m & 2047;
      qkv[(size_t)which*SZ_BHTD + (size_t)((b*16 + h)*2048 + t)*64 + d] = f2bf(acc[ns][r]);
    }
  }
}

// Per (b,h,chunk): intra-chunk retention, chunk summary U, plain K^T V partial.
__global__ __launch_bounds__(256) void k_r1(const uint16_t* __restrict__ qkv, float* __restrict__ ret,
                                            uint16_t* __restrict__ U, uint16_t* __restrict__ ckp){
  __shared__ float Qf[64*65];
  __shared__ float KT[64*65];
  __shared__ float VT[64*65];
  __shared__ float Pl[64*65];
  __shared__ float tab[65];
  const int tid = threadIdx.x, blk = blockIdx.x;
  const int bh = blk >> 5, c = blk & 31, h = bh & 15;
  const float g = 1.0f - exp2f(-(float)(5 + h));
  if (tid <= 64) tab[tid] = powf(g, (float)tid);
  const uint16_t* Qg = qkv + (size_t)bh*SZ_HTD + c*4096;
  const uint16_t* Kg = Qg + SZ_BHTD;
  const uint16_t* Vg = Qg + 2*(size_t)SZ_BHTD;
  for (int idx = tid; idx < 4096; idx += 256){
    int r = idx >> 6, cc = idx & 63;
    Qf[r*65 + cc] = bf2f(Qg[idx]);
    KT[cc*65 + r] = bf2f(Kg[idx]);
    VT[cc*65 + r] = bf2f(Vg[idx]);
  }
  __syncthreads();
  const int ty = tid >> 4, tx = tid & 15;
  const int i0 = ty*4, j0 = tx*4;
  // P = Q K^T (C[i][j] = sum_e Q[i][e] K[j][e] = sum_e Qf[i][e]*KT[e][j])
  float p[4][4] = {};
  for (int e = 0; e < 64; ++e){
    float a[4], b[4];
    #pragma unroll
    for (int u = 0; u < 4; ++u) a[u] = Qf[(i0+u)*65 + e];
    #pragma unroll
    for (int u = 0; u < 4; ++u) b[u] = KT[e*65 + j0 + u];
    #pragma unroll
    for (int ii = 0; ii < 4; ++ii)
      #pragma unroll
      for (int jj = 0; jj < 4; ++jj) p[ii][jj] = fmaf(a[ii], b[jj], p[ii][jj]);
  }
  #pragma unroll
  for (int ii = 0; ii < 4; ++ii)
    #pragma unroll
    for (int jj = 0; jj < 4; ++jj){
      int i = i0 + ii, j = j0 + jj;
      Pl[i*65 + j] = (i >= j) ? p[ii][jj]*tab[i - j] : 0.0f;
    }
  __syncthreads();
  // intra = P' @ V  (C[i][d] = sum_s Pl[i][s] VT[d][s])
  float ci[4][4] = {};
  for (int s = 0; s < 64; ++s){
    float a[4], b[4];
    #pragma unroll
    for (int u = 0; u < 4; ++u) a[u] = Pl[(i0+u)*65 + s];
    #pragma unroll
    for (int u = 0; u < 4; ++u) b[u] = VT[(j0+u)*65 + s];
    #pragma unroll
    for (int ii = 0; ii < 4; ++ii)
      #pragma unroll
      for (int jj = 0; jj < 4; ++jj) ci[ii][jj] = fmaf(a[ii], b[jj], ci[ii][jj]);
  }
  const size_t rbase = (size_t)bh*2048 + c*64;
  #pragma unroll
  for (int ii = 0; ii < 4; ++ii)
    #pragma unroll
    for (int jj = 0; jj < 4; ++jj)
      ret[(rbase + i0 + ii)*64 + j0 + jj] = ci[ii][jj];
  // U[e][d] = sum_s gamma^{63-s} K[s][e] V[s][d];  CK[e][d] = sum_s K[s][e] V[s][d]
  float cu[4][4] = {}, ck[4][4] = {};
  for (int s = 0; s < 64; ++s){
    float wgt = tab[63 - s];
    float a[4], b[4];
    #pragma unroll
    for (int u = 0; u < 4; ++u) a[u] = KT[(i0+u)*65 + s];
    #pragma unroll
    for (int u = 0; u < 4; ++u) b[u] = VT[(j0+u)*65 + s];
    #pragma unroll
    for (int ii = 0; ii < 4; ++ii)
      #pragma unroll
      for (int jj = 0; jj < 4; ++jj){
        float ab = a[ii]*b[jj];
        ck[ii][jj] += ab;
        cu[ii][jj] = fmaf(ab, wgt, cu[ii][jj]);
      }
  }
  const size_t ob = (size_t)blk*4096;
  #pragma unroll
  for (int ii = 0; ii < 4; ++ii)
    #pragma unroll
    for (int jj = 0; jj < 4; ++jj){
      U[ob + (i0+ii)*64 + j0 + jj]   = f2bf(cu[ii][jj]);
      ckp[ob + (i0+ii)*64 + j0 + jj] = f2bf(ck[ii][jj]);
    }
}

// Scan over chunks: S[c] = state BEFORE chunk c (stored transposed: S[c][d][e] = A[e][d])
__global__ __launch_bounds__(256) void k_r2(const uint16_t* __restrict__ U, uint16_t* __restrict__ S){
  const int tid = threadIdx.x, bh = blockIdx.x, h = bh & 15;
  const float g = 1.0f - exp2f(-(float)(5 + h));
  const float g64 = powf(g, 64.0f);
  float st[16];
  #pragma unroll
  for (int q = 0; q < 16; ++q) st[q] = 0.0f;
  for (int c = 0; c < 32; ++c){
    const size_t base = ((size_t)bh*32 + c)*4096;
    #pragma unroll
    for (int q = 0; q < 16; ++q){
      int idx = q*256 + tid;          // owned (d,e): d=idx>>6, e=idx&63
      S[base + idx] = f2bf(st[q]);
      int d = idx >> 6, e = idx & 63;
      st[q] = fmaf(g64, st[q], bf2f(U[base + e*64 + d]));
    }
  }
}

// inter[i][d] = gamma^{i+1} * sum_e Q[i][e] * S[d][e];  ret +=
__global__ __launch_bounds__(256) void k_r3(const uint16_t* __restrict__ qkv, const uint16_t* __restrict__ S,
                                            float* __restrict__ ret){
  __shared__ float Qf[64*65];
  __shared__ float Sf[64*65];
  __shared__ float tab[65];
  const int tid = threadIdx.x, blk = blockIdx.x;
  const int bh = blk >> 5, c = blk & 31, h = bh & 15;
  if (c == 0) return;                 // state before chunk 0 is zero
  const float g = 1.0f - exp2f(-(float)(5 + h));
  if (tid <= 64) tab[tid] = powf(g, (float)tid);
  const uint16_t* Qg = qkv + (size_t)bh*SZ_HTD + c*4096;
  const uint16_t* Sg = S + (size_t)blk*4096;
  for (int idx = tid; idx < 4096; idx += 256){
    int r = idx >> 6, cc = idx & 63;
    Qf[r*65 + cc] = bf2f(Qg[idx]);
    Sf[r*65 + cc] = bf2f(Sg[idx]);    // Sf[d][e]
  }
  __syncthreads();
  const int ty = tid >> 4, tx = tid & 15;
  const int i0 = ty*4, j0 = tx*4;
  float ci[4][4] = {};
  for (int e = 0; e < 64; ++e){
    float a[4], b[4];
    #pragma unroll
    for (int u = 0; u < 4; ++u) a[u] = Qf[(i0+u)*65 + e];
    #pragma unroll
    for (int u = 0; u < 4; ++u) b[u] = Sf[(j0+u)*65 + e];
    #pragma unroll
    for (int ii = 0; ii < 4; ++ii)
      #pragma unroll
      for (int jj = 0; jj < 4; ++jj) ci[ii][jj] = fmaf(a[ii], b[jj], ci[ii][jj]);
  }
  const size_t rbase = (size_t)bh*2048 + c*64;
  #pragma unroll
  for (int ii = 0; ii < 4; ++ii){
    const float sc = tab[i0 + ii + 1];
    #pragma unroll
    for (int jj = 0; jj < 4; ++jj){
      const size_t o = (rbase + i0 + ii)*64 + j0 + jj;
      ret[o] += sc*ci[ii][jj];
    }
  }
}

// cross intra-chunk: pp = Q @ past_kv; cross_local[i][e] = sum_{j>=i} gamma^{j-i} pp[j][e]
__global__ __launch_bounds__(256) void k_x1(const uint16_t* __restrict__ qkv, const float* __restrict__ pkv,
                                            float* __restrict__ ret, float* __restrict__ headv){
  __shared__ float Qf[64*65];
  __shared__ float PT[64*65];
  __shared__ float ppT[64*65];
  __shared__ float tab[65];
  const int tid = threadIdx.x, blk = blockIdx.x;
  const int bh = blk >> 5, c = blk & 31, h = bh & 15;
  const float g = 1.0f - exp2f(-(float)(5 + h));
  if (tid <= 64) tab[tid] = powf(g, (float)tid);
  const uint16_t* Qg = qkv + (size_t)bh*SZ_HTD + c*4096;
  for (int idx = tid; idx < 4096; idx += 256){
    int r = idx >> 6, cc = idx & 63;
    Qf[r*65 + cc] = bf2f(Qg[idx]);
    PT[cc*65 + r] = pkv[h*4096 + idx];   // PT[e][d] = pkv[h][d][e]
  }
  __syncthreads();
  const int ty = tid >> 4, tx = tid & 15;
  const int i0 = ty*4, j0 = tx*4;
  float cp[4][4] = {};
  for (int d = 0; d < 64; ++d){
    float a[4], b[4];
    #pragma unroll
    for (int u = 0; u < 4; ++u) a[u] = Qf[(i0+u)*65 + d];
    #pragma unroll
    for (int u = 0; u < 4; ++u) b[u] = PT[(j0+u)*65 + d];
    #pragma unroll
    for (int ii = 0; ii < 4; ++ii)
      #pragma unroll
      for (int jj = 0; jj < 4; ++jj) cp[ii][jj] = fmaf(a[ii], b[jj], cp[ii][jj]);
  }
  #pragma unroll
  for (int ii = 0; ii < 4; ++ii)
    #pragma unroll
    for (int jj = 0; jj < 4; ++jj)
      ppT[(j0+jj)*65 + i0 + ii] = cp[ii][jj];
  __syncthreads();
  float cx[4][4] = {};
  for (int j = 0; j < 64; ++j){
    float a[4], b[4];
    #pragma unroll
    for (int u = 0; u < 4; ++u) b[u] = ppT[(j0+u)*65 + j];
    #pragma unroll
    for (int u = 0; u < 4; ++u) a[u] = (j >= i0 + u) ? tab[j - i0 - u] : 0.0f;
    #pragma unroll
    for (int ii = 0; ii < 4; ++ii)
      #pragma unroll
      for (int jj = 0; jj < 4; ++jj) cx[ii][jj] = fmaf(a[ii], b[jj], cx[ii][jj]);
  }
  const size_t rbase = (size_t)bh*2048 + c*64;
  #pragma unroll
  for (int ii = 0; ii < 4; ++ii)
    #pragma unroll
    for (int jj = 0; jj < 4; ++jj)
      ret[(rbase + i0 + ii)*64 + j0 + jj] += cx[ii][jj];
  if (ty == 0){
    #pragma unroll
    for (int jj = 0; jj < 4; ++jj)
      headv[(size_t)blk*64 + j0 + jj] = cx[0][jj];
  }
}

// backward chunk scan: tail[c] = R_{c+1}, R_c = head[c] + gamma^64 * R_{c+1}
__global__ __launch_bounds__(256) void k_x2(const float* __restrict__ headv, float* __restrict__ tailv){
  const int lin = blockIdx.x*256 + threadIdx.x;   // 4096 = B*H*DH
  const int bh = lin >> 6, e = lin & 63, h = bh & 15;
  const float g = 1.0f - exp2f(-(float)(5 + h));
  const float g64 = powf(g, 64.0f);
  float R = 0.0f;
  for (int c = 31; c >= 0; --c){
    const size_t o = ((size_t)bh*32 + c)*64 + e;
    tailv[o] = R;
    R = fmaf(g64, R, headv[o]);
  }
}

// add cross tail term, accumulate per-batch sum/sumsq
__global__ __launch_bounds__(256) void k_fin(float* __restrict__ ret, const float* __restrict__ tailv,
                                             float* __restrict__ stats){
  __shared__ float tab[65];
  __shared__ float ps[8];
  const int b = blockIdx.y;
  const int l0 = blockIdx.x*1024;
  const int h = l0 >> 17;
  const float g = 1.0f - exp2f(-(float)(5 + h));
  if (threadIdx.x <= 64) tab[threadIdx.x] = powf(g, (float)threadIdx.x);
  __syncthreads();
  const int l = l0 + threadIdx.x*4;
  const size_t gi = (size_t)b*2097152 + l;
  float4 v = *(float4*)&ret[gi];
  const int t = (l >> 6) & 2047, i = t & 63, d0 = l & 63;
  const size_t tr = ((size_t)(b*16 + h)*32 + (t >> 6))*64 + d0;
  const float4 tl = *(const float4*)&tailv[tr];
  const float sc = tab[64 - i];
  v.x = fmaf(sc, tl.x, v.x); v.y = fmaf(sc, tl.y, v.y);
  v.z = fmaf(sc, tl.z, v.z); v.w = fmaf(sc, tl.w, v.w);
  *(float4*)&ret[gi] = v;
  float s = v.x + v.y + v.z + v.w;
  float s2 = v.x*v.x + v.y*v.y + v.z*v.z + v.w*v.w;
  #pragma unroll
  for (int off = 32; off > 0; off >>= 1){
    s  += __shfl_down(s, off);
    s2 += __shfl_down(s2, off);
  }
  const int wv = threadIdx.x >> 6;
  if ((threadIdx.x & 63) == 0){ ps[wv*2] = s; ps[wv*2+1] = s2; }
  __syncthreads();
  if (threadIdx.x == 0){
    atomicAdd(&stats[b*2],   ps[0] + ps[2] + ps[4] + ps[6]);
    atomicAdd(&stats[b*2+1], ps[1] + ps[3] + ps[5] + ps[7]);
  }
}

// GroupNorm apply + layout to [B,T,NE]
__global__ __launch_bounds__(256) void k_norm(const float* __restrict__ ret, const float* __restrict__ stats,
                                              const float* __restrict__ gw, const float* __restrict__ gb,
                                              float* __restrict__ out){
  const int o = (blockIdx.x*256 + threadIdx.x)*4;
  const int b = o >> 21, t = (o >> 10) & 2047, cch = o & 1023;
  const int h = cch >> 6, d = cch & 63;
  const float inv = 1.0f/2097152.0f;
  const float mu = stats[b*2]*inv;
  const float var = stats[b*2+1]*inv - mu*mu;
  const float rs = rsqrtf(var + 1e-5f);
  const float w = gw[h]*rs, bb = gb[h];
  const float4 v = *(const float4*)&ret[((size_t)(b*16 + h)*2048 + t)*64 + d];
  float4 r;
  r.x = (v.x - mu)*w + bb; r.y = (v.y - mu)*w + bb;
  r.z = (v.z - mu)*w + bb; r.w = (v.w - mu)*w + bb;
  *(float4*)&out[o] = r;
}

// current_kv = gamma*past_kv + mean_b K^T V  (reduce 128 partials)
__global__ __launch_bounds__(256) void k_ckb(const float* __restrict__ pkv, const uint16_t* __restrict__ ckp,
                                             float* __restrict__ out2){
  const int lin = blockIdx.x*256 + threadIdx.x;  // 16384
  const int i = lin*4;
  const int h = i >> 12, de = i & 4095;
  const float g = 1.0f - exp2f(-(float)(5 + h));
  float acc[4] = {0.0f, 0.0f, 0.0f, 0.0f};
  for (int b = 0; b < 4; ++b){
    const uint16_t* base = ckp + ((size_t)(b*16 + h)*32)*4096 + de;
    for (int c = 0; c < 32; ++c){
      #pragma unroll
      for (int u = 0; u < 4; ++u) acc[u] += bf2f(base[(size_t)c*4096 + u]);
    }
  }
  #pragma unroll
  for (int u = 0; u < 4; ++u)
    out2[i + u] = fmaf(g, pkv[i + u], 0.25f*acc[u]);
}

extern "C" void kernel_launch(void* const* d_in, const int* in_sizes, int n_in,
                              void* d_out, int out_size, void* d_ws, size_t ws_size,
                              hipStream_t stream){
  const float* x   = (const float*)d_in[0];
  const float* pkv = (const float*)d_in[1];
  const float* Wq  = (const float*)d_in[2];
  const float* Wk  = (const float*)d_in[3];
  const float* Wv  = (const float*)d_in[4];
  const float* gnw = (const float*)d_in[5];
  const float* gnb = (const float*)d_in[6];
  float* out  = (float*)d_out;
  float* out2 = out + 8388608;

  char* ws = (char*)d_ws;
  size_t off = 0;
  float*    stats = (float*)(ws + off);    off += 256;
  uint16_t* Xb    = (uint16_t*)(ws + off); off += (size_t)8388608*2;
  uint16_t* Wt    = (uint16_t*)(ws + off); off += (size_t)3145728*2;
  uint16_t* QKV   = (uint16_t*)(ws + off); off += (size_t)3*8388608*2;
  float*    ret   = (float*)(ws + off);    off += (size_t)8388608*4;
  uint16_t* U     = (uint16_t*)(ws + off); off += (size_t)8388608*2;
  uint16_t* S     = (uint16_t*)(ws + off); off += (size_t)8388608*2;
  uint16_t* CKp   = (uint16_t*)(ws + off); off += (size_t)8388608*2;
  float*    headv = (float*)(ws + off);    off += (size_t)131072*4;
  float*    tailv = (float*)(ws + off);    off += (size_t)131072*4;

  hipMemsetAsync(stats, 0, 256, stream);
  k_conv_x<<<8192, 256, 0, stream>>>(x, Xb);
  k_conv_w<<<dim3(16,16,3), 256, 0, stream>>>(Wq, Wk, Wv, Wt);
  k_gemm<<<dim3(128,48), 256, 0, stream>>>(Xb, Wt, QKV);
  k_r1<<<2048, 256, 0, stream>>>(QKV, ret, U, CKp);
  k_r2<<<64, 256, 0, stream>>>(U, S);
  k_r3<<<2048, 256, 0, stream>>>(QKV, S, ret);
  k_x1<<<2048, 256, 0, stream>>>(QKV, pkv, ret, headv);
  k_x2<<<16, 256, 0, stream>>>(headv, tailv);
  k_fin<<<dim3(2048,4), 256, 0, stream>>>(ret, tailv, stats);
  k_norm<<<8192, 256, 0, stream>>>(ret, stats, gnw, gnb, out);
  k_ckb<<<64, 256, 0, stream>>>(pkv, CKp, out2);
}

// Round 2
// 487.713 us; speedup vs baseline: 1.4110x; 1.4110x over previous
//
#include <hip/hip_runtime.h>
#include <stdint.h>

typedef float v4f __attribute__((ext_vector_type(4)));
typedef short v8s __attribute__((ext_vector_type(8)));

#define SZ_BHTD 8388608   // B*H*T*DH
#define SZ_HTD  131072    // T*DH

__device__ __forceinline__ uint16_t f2bf(float f){
  uint32_t u = __float_as_uint(f);
  u += 0x7fffu + ((u >> 16) & 1u);
  return (uint16_t)(u >> 16);
}
__device__ __forceinline__ float bf2f(uint16_t v){
  return __uint_as_float(((uint32_t)v) << 16);
}

// x fp32 -> bf16 (4 elems/thread)
__global__ __launch_bounds__(256) void k_conv_x(const float* __restrict__ x, uint16_t* __restrict__ xb){
  int i = blockIdx.x*256 + threadIdx.x;
  const float4 v = ((const float4*)x)[i];
  ushort4 o; o.x = f2bf(v.x); o.y = f2bf(v.y); o.z = f2bf(v.z); o.w = f2bf(v.w);
  ((ushort4*)xb)[i] = o;
}

// Wq/Wk/Wv fp32 [1024][1024] -> Wt bf16 [3072][1024], Wt[n][k] = W[k][n]
__global__ __launch_bounds__(256) void k_conv_w(const float* __restrict__ Wq, const float* __restrict__ Wk,
                                                const float* __restrict__ Wv, uint16_t* __restrict__ wt){
  __shared__ float t[64][65];
  const float* W = blockIdx.z==0 ? Wq : (blockIdx.z==1 ? Wk : Wv);
  int n0 = blockIdx.x*64, k0 = blockIdx.y*64;
  for (int idx = threadIdx.x; idx < 4096; idx += 256){
    int r = idx >> 6, c = idx & 63;
    t[r][c] = W[(k0+r)*1024 + n0 + c];
  }
  __syncthreads();
  for (int idx = threadIdx.x; idx < 4096; idx += 256){
    int r = idx >> 6, c = idx & 63;   // r: local n, c: local k
    wt[(size_t)(blockIdx.z*1024 + n0 + r)*1024 + k0 + c] = f2bf(t[c][r]);
  }
}

// QKV = Xb @ W (B-operand given transposed). Out bf16 [3][B][H][T][DH].
__global__ __launch_bounds__(256) void k_gemm(const uint16_t* __restrict__ Xb, const uint16_t* __restrict__ Wt,
                                              uint16_t* __restrict__ qkv){
  __shared__ uint16_t As[64*72];
  __shared__ uint16_t Bs[64*72];
  const int tid = threadIdx.x;
  const int lane = tid & 63, w = tid >> 6;
  const int quad = lane >> 4, l16 = lane & 15;
  const int bm = blockIdx.x, bn = blockIdx.y;
  v4f acc[4] = {{0,0,0,0},{0,0,0,0},{0,0,0,0},{0,0,0,0}};
  const int rowA = tid >> 3, col8 = (tid & 7)*8;
  const uint16_t* xa = Xb + (size_t)(bm*64)*1024;
  const uint16_t* wb = Wt + (size_t)(bn*64)*1024;
  for (int k0 = 0; k0 < 1024; k0 += 64){
    *(uint4*)&As[rowA*72 + col8]      = *(const uint4*)&xa[(size_t)rowA*1024 + k0 + col8];
    *(uint4*)&As[(rowA+32)*72 + col8] = *(const uint4*)&xa[(size_t)(rowA+32)*1024 + k0 + col8];
    *(uint4*)&Bs[rowA*72 + col8]      = *(const uint4*)&wb[(size_t)rowA*1024 + k0 + col8];
    *(uint4*)&Bs[(rowA+32)*72 + col8] = *(const uint4*)&wb[(size_t)(rowA+32)*1024 + k0 + col8];
    __syncthreads();
    #pragma unroll
    for (int kk = 0; kk < 64; kk += 32){
      v8s a = *(v8s*)&As[(w*16 + l16)*72 + kk + quad*8];
      #pragma unroll
      for (int ns = 0; ns < 4; ++ns){
        v8s b = *(v8s*)&Bs[(ns*16 + l16)*72 + kk + quad*8];
        acc[ns] = __builtin_amdgcn_mfma_f32_16x16x32_bf16(a, b, acc[ns], 0, 0, 0);
      }
    }
    __syncthreads();
  }
  #pragma unroll
  for (int ns = 0; ns < 4; ++ns){
    int n = bn*64 + ns*16 + l16;
    int which = n >> 10, cch = n & 1023;
    int h = cch >> 6, d = cch & 63;
    #pragma unroll
    for (int r = 0; r < 4; ++r){
      int m = bm*64 + w*16 + quad*4 + r;
      int b = m >> 11, t = m & 2047;
      qkv[(size_t)which*SZ_BHTD + (size_t)((b*16 + h)*2048 + t)*64 + d] = f2bf(acc[ns][r]);
    }
  }
}

// Per (b,h,chunk): intra-chunk retention, chunk summary U, plain K^T V partial.
__global__ __launch_bounds__(256) void k_r1(const uint16_t* __restrict__ qkv, float* __restrict__ ret,
                                            uint16_t* __restrict__ U, uint16_t* __restrict__ ckp){
  __shared__ float Qf[64*65];
  __shared__ float KT[64*65];
  __shared__ float VT[64*65];
  __shared__ float Pl[64*65];
  __shared__ float tab[65];
  const int tid = threadIdx.x, blk = blockIdx.x;
  const int bh = blk >> 5, c = blk & 31, h = bh & 15;
  const float g = 1.0f - exp2f(-(float)(5 + h));
  if (tid <= 64) tab[tid] = powf(g, (float)tid);
  const uint16_t* Qg = qkv + (size_t)bh*SZ_HTD + c*4096;
  const uint16_t* Kg = Qg + SZ_BHTD;
  const uint16_t* Vg = Qg + 2*(size_t)SZ_BHTD;
  for (int idx = tid; idx < 4096; idx += 256){
    int r = idx >> 6, cc = idx & 63;
    Qf[r*65 + cc] = bf2f(Qg[idx]);
    KT[cc*65 + r] = bf2f(Kg[idx]);
    VT[cc*65 + r] = bf2f(Vg[idx]);
  }
  __syncthreads();
  const int ty = tid >> 4, tx = tid & 15;
  const int i0 = ty*4, j0 = tx*4;
  // P = Q K^T (C[i][j] = sum_e Q[i][e] K[j][e] = sum_e Qf[i][e]*KT[e][j])
  float p[4][4] = {};
  for (int e = 0; e < 64; ++e){
    float a[4], b[4];
    #pragma unroll
    for (int u = 0; u < 4; ++u) a[u] = Qf[(i0+u)*65 + e];
    #pragma unroll
    for (int u = 0; u < 4; ++u) b[u] = KT[e*65 + j0 + u];
    #pragma unroll
    for (int ii = 0; ii < 4; ++ii)
      #pragma unroll
      for (int jj = 0; jj < 4; ++jj) p[ii][jj] = fmaf(a[ii], b[jj], p[ii][jj]);
  }
  #pragma unroll
  for (int ii = 0; ii < 4; ++ii)
    #pragma unroll
    for (int jj = 0; jj < 4; ++jj){
      int i = i0 + ii, j = j0 + jj;
      Pl[i*65 + j] = (i >= j) ? p[ii][jj]*tab[i - j] : 0.0f;
    }
  __syncthreads();
  // intra = P' @ V  (C[i][d] = sum_s Pl[i][s] VT[d][s])
  float ci[4][4] = {};
  for (int s = 0; s < 64; ++s){
    float a[4], b[4];
    #pragma unroll
    for (int u = 0; u < 4; ++u) a[u] = Pl[(i0+u)*65 + s];
    #pragma unroll
    for (int u = 0; u < 4; ++u) b[u] = VT[(j0+u)*65 + s];
    #pragma unroll
    for (int ii = 0; ii < 4; ++ii)
      #pragma unroll
      for (int jj = 0; jj < 4; ++jj) ci[ii][jj] = fmaf(a[ii], b[jj], ci[ii][jj]);
  }
  const size_t rbase = (size_t)bh*2048 + c*64;
  #pragma unroll
  for (int ii = 0; ii < 4; ++ii)
    #pragma unroll
    for (int jj = 0; jj < 4; ++jj)
      ret[(rbase + i0 + ii)*64 + j0 + jj] = ci[ii][jj];
  // U[e][d] = sum_s gamma^{63-s} K[s][e] V[s][d];  CK[e][d] = sum_s K[s][e] V[s][d]
  float cu[4][4] = {}, ck[4][4] = {};
  for (int s = 0; s < 64; ++s){
    float wgt = tab[63 - s];
    float a[4], b[4];
    #pragma unroll
    for (int u = 0; u < 4; ++u) a[u] = KT[(i0+u)*65 + s];
    #pragma unroll
    for (int u = 0; u < 4; ++u) b[u] = VT[(j0+u)*65 + s];
    #pragma unroll
    for (int ii = 0; ii < 4; ++ii)
      #pragma unroll
      for (int jj = 0; jj < 4; ++jj){
        float ab = a[ii]*b[jj];
        ck[ii][jj] += ab;
        cu[ii][jj] = fmaf(ab, wgt, cu[ii][jj]);
      }
  }
  const size_t ob = (size_t)blk*4096;
  #pragma unroll
  for (int ii = 0; ii < 4; ++ii)
    #pragma unroll
    for (int jj = 0; jj < 4; ++jj){
      U[ob + (i0+ii)*64 + j0 + jj]   = f2bf(cu[ii][jj]);
      ckp[ob + (i0+ii)*64 + j0 + jj] = f2bf(ck[ii][jj]);
    }
}

// Scan over chunks: S[c] = state BEFORE chunk c (stored transposed: S[c][d][e] = A[e][d])
__global__ __launch_bounds__(256) void k_r2(const uint16_t* __restrict__ U, uint16_t* __restrict__ S){
  const int tid = threadIdx.x, bh = blockIdx.x, h = bh & 15;
  const float g = 1.0f - exp2f(-(float)(5 + h));
  const float g64 = powf(g, 64.0f);
  float st[16];
  #pragma unroll
  for (int q = 0; q < 16; ++q) st[q] = 0.0f;
  for (int c = 0; c < 32; ++c){
    const size_t base = ((size_t)bh*32 + c)*4096;
    #pragma unroll
    for (int q = 0; q < 16; ++q){
      int idx = q*256 + tid;          // owned (d,e): d=idx>>6, e=idx&63
      S[base + idx] = f2bf(st[q]);
      int d = idx >> 6, e = idx & 63;
      st[q] = fmaf(g64, st[q], bf2f(U[base + e*64 + d]));
    }
  }
}

// inter[i][d] = gamma^{i+1} * sum_e Q[i][e] * S[d][e];  ret +=
__global__ __launch_bounds__(256) void k_r3(const uint16_t* __restrict__ qkv, const uint16_t* __restrict__ S,
                                            float* __restrict__ ret){
  __shared__ float Qf[64*65];
  __shared__ float Sf[64*65];
  __shared__ float tab[65];
  const int tid = threadIdx.x, blk = blockIdx.x;
  const int bh = blk >> 5, c = blk & 31, h = bh & 15;
  if (c == 0) return;                 // state before chunk 0 is zero
  const float g = 1.0f - exp2f(-(float)(5 + h));
  if (tid <= 64) tab[tid] = powf(g, (float)tid);
  const uint16_t* Qg = qkv + (size_t)bh*SZ_HTD + c*4096;
  const uint16_t* Sg = S + (size_t)blk*4096;
  for (int idx = tid; idx < 4096; idx += 256){
    int r = idx >> 6, cc = idx & 63;
    Qf[r*65 + cc] = bf2f(Qg[idx]);
    Sf[r*65 + cc] = bf2f(Sg[idx]);    // Sf[d][e]
  }
  __syncthreads();
  const int ty = tid >> 4, tx = tid & 15;
  const int i0 = ty*4, j0 = tx*4;
  float ci[4][4] = {};
  for (int e = 0; e < 64; ++e){
    float a[4], b[4];
    #pragma unroll
    for (int u = 0; u < 4; ++u) a[u] = Qf[(i0+u)*65 + e];
    #pragma unroll
    for (int u = 0; u < 4; ++u) b[u] = Sf[(j0+u)*65 + e];
    #pragma unroll
    for (int ii = 0; ii < 4; ++ii)
      #pragma unroll
      for (int jj = 0; jj < 4; ++jj) ci[ii][jj] = fmaf(a[ii], b[jj], ci[ii][jj]);
  }
  const size_t rbase = (size_t)bh*2048 + c*64;
  #pragma unroll
  for (int ii = 0; ii < 4; ++ii){
    const float sc = tab[i0 + ii + 1];
    #pragma unroll
    for (int jj = 0; jj < 4; ++jj){
      const size_t o = (rbase + i0 + ii)*64 + j0 + jj;
      ret[o] += sc*ci[ii][jj];
    }
  }
}

// cross intra-chunk: pp = Q @ past_kv; cross_local[i][e] = sum_{j>=i} gamma^{j-i} pp[j][e]
__global__ __launch_bounds__(256) void k_x1(const uint16_t* __restrict__ qkv, const float* __restrict__ pkv,
                                            float* __restrict__ ret, float* __restrict__ headv){
  __shared__ float Qf[64*65];
  __shared__ float PT[64*65];
  __shared__ float ppT[64*65];
  __shared__ float tab[65];
  const int tid = threadIdx.x, blk = blockIdx.x;
  const int bh = blk >> 5, c = blk & 31, h = bh & 15;
  const float g = 1.0f - exp2f(-(float)(5 + h));
  if (tid <= 64) tab[tid] = powf(g, (float)tid);
  const uint16_t* Qg = qkv + (size_t)bh*SZ_HTD + c*4096;
  for (int idx = tid; idx < 4096; idx += 256){
    int r = idx >> 6, cc = idx & 63;
    Qf[r*65 + cc] = bf2f(Qg[idx]);
    PT[cc*65 + r] = pkv[h*4096 + idx];   // PT[e][d] = pkv[h][d][e]
  }
  __syncthreads();
  const int ty = tid >> 4, tx = tid & 15;
  const int i0 = ty*4, j0 = tx*4;
  float cp[4][4] = {};
  for (int d = 0; d < 64; ++d){
    float a[4], b[4];
    #pragma unroll
    for (int u = 0; u < 4; ++u) a[u] = Qf[(i0+u)*65 + d];
    #pragma unroll
    for (int u = 0; u < 4; ++u) b[u] = PT[(j0+u)*65 + d];
    #pragma unroll
    for (int ii = 0; ii < 4; ++ii)
      #pragma unroll
      for (int jj = 0; jj < 4; ++jj) cp[ii][jj] = fmaf(a[ii], b[jj], cp[ii][jj]);
  }
  #pragma unroll
  for (int ii = 0; ii < 4; ++ii)
    #pragma unroll
    for (int jj = 0; jj < 4; ++jj)
      ppT[(j0+jj)*65 + i0 + ii] = cp[ii][jj];
  __syncthreads();
  float cx[4][4] = {};
  for (int j = 0; j < 64; ++j){
    float a[4], b[4];
    #pragma unroll
    for (int u = 0; u < 4; ++u) b[u] = ppT[(j0+u)*65 + j];
    #pragma unroll
    for (int u = 0; u < 4; ++u) a[u] = (j >= i0 + u) ? tab[j - i0 - u] : 0.0f;
    #pragma unroll
    for (int ii = 0; ii < 4; ++ii)
      #pragma unroll
      for (int jj = 0; jj < 4; ++jj) cx[ii][jj] = fmaf(a[ii], b[jj], cx[ii][jj]);
  }
  const size_t rbase = (size_t)bh*2048 + c*64;
  #pragma unroll
  for (int ii = 0; ii < 4; ++ii)
    #pragma unroll
    for (int jj = 0; jj < 4; ++jj)
      ret[(rbase + i0 + ii)*64 + j0 + jj] += cx[ii][jj];
  if (ty == 0){
    #pragma unroll
    for (int jj = 0; jj < 4; ++jj)
      headv[(size_t)blk*64 + j0 + jj] = cx[0][jj];
  }
}

// backward chunk scan: tail[c] = R_{c+1}, R_c = head[c] + gamma^64 * R_{c+1}
__global__ __launch_bounds__(256) void k_x2(const float* __restrict__ headv, float* __restrict__ tailv){
  const int lin = blockIdx.x*256 + threadIdx.x;   // 4096 = B*H*DH
  const int bh = lin >> 6, e = lin & 63, h = bh & 15;
  const float g = 1.0f - exp2f(-(float)(5 + h));
  const float g64 = powf(g, 64.0f);
  float R = 0.0f;
  for (int c = 31; c >= 0; --c){
    const size_t o = ((size_t)bh*32 + c)*64 + e;
    tailv[o] = R;
    R = fmaf(g64, R, headv[o]);
  }
}

// add cross tail term, per-block partial sum/sumsq (NO atomics — two-stage reduce)
__global__ __launch_bounds__(256) void k_fin(float* __restrict__ ret, const float* __restrict__ tailv,
                                             float2* __restrict__ pb){
  __shared__ float tab[65];
  __shared__ float ps[8];
  const int b = blockIdx.y;
  const int l0 = blockIdx.x*1024;
  const int h = l0 >> 17;
  const float g = 1.0f - exp2f(-(float)(5 + h));
  if (threadIdx.x <= 64) tab[threadIdx.x] = powf(g, (float)threadIdx.x);
  __syncthreads();
  const int l = l0 + threadIdx.x*4;
  const size_t gi = (size_t)b*2097152 + l;
  float4 v = *(float4*)&ret[gi];
  const int t = (l >> 6) & 2047, i = t & 63, d0 = l & 63;
  const size_t tr = ((size_t)(b*16 + h)*32 + (t >> 6))*64 + d0;
  const float4 tl = *(const float4*)&tailv[tr];
  const float sc = tab[64 - i];
  v.x = fmaf(sc, tl.x, v.x); v.y = fmaf(sc, tl.y, v.y);
  v.z = fmaf(sc, tl.z, v.z); v.w = fmaf(sc, tl.w, v.w);
  *(float4*)&ret[gi] = v;
  float s = v.x + v.y + v.z + v.w;
  float s2 = v.x*v.x + v.y*v.y + v.z*v.z + v.w*v.w;
  #pragma unroll
  for (int off = 32; off > 0; off >>= 1){
    s  += __shfl_down(s, off);
    s2 += __shfl_down(s2, off);
  }
  const int wv = threadIdx.x >> 6;
  if ((threadIdx.x & 63) == 0){ ps[wv*2] = s; ps[wv*2+1] = s2; }
  __syncthreads();
  if (threadIdx.x == 0){
    float2 o; o.x = ps[0] + ps[2] + ps[4] + ps[6];
    o.y = ps[1] + ps[3] + ps[5] + ps[7];
    pb[(size_t)b*2048 + blockIdx.x] = o;
  }
}

// reduce 2048 per-block partials per batch -> stats[b*2], stats[b*2+1]
__global__ __launch_bounds__(256) void k_stats(const float2* __restrict__ pb, float* __restrict__ stats){
  __shared__ float ps[8];
  const int b = blockIdx.x;
  float s = 0.0f, s2 = 0.0f;
  for (int i = threadIdx.x; i < 2048; i += 256){
    const float2 p = pb[(size_t)b*2048 + i];
    s += p.x; s2 += p.y;
  }
  #pragma unroll
  for (int off = 32; off > 0; off >>= 1){
    s  += __shfl_down(s, off);
    s2 += __shfl_down(s2, off);
  }
  const int wv = threadIdx.x >> 6;
  if ((threadIdx.x & 63) == 0){ ps[wv*2] = s; ps[wv*2+1] = s2; }
  __syncthreads();
  if (threadIdx.x == 0){
    stats[b*2]   = ps[0] + ps[2] + ps[4] + ps[6];
    stats[b*2+1] = ps[1] + ps[3] + ps[5] + ps[7];
  }
}

// GroupNorm apply + layout to [B,T,NE]
__global__ __launch_bounds__(256) void k_norm(const float* __restrict__ ret, const float* __restrict__ stats,
                                              const float* __restrict__ gw, const float* __restrict__ gb,
                                              float* __restrict__ out){
  const int o = (blockIdx.x*256 + threadIdx.x)*4;
  const int b = o >> 21, t = (o >> 10) & 2047, cch = o & 1023;
  const int h = cch >> 6, d = cch & 63;
  const float inv = 1.0f/2097152.0f;
  const float mu = stats[b*2]*inv;
  const float var = stats[b*2+1]*inv - mu*mu;
  const float rs = rsqrtf(var + 1e-5f);
  const float w = gw[h]*rs, bb = gb[h];
  const float4 v = *(const float4*)&ret[((size_t)(b*16 + h)*2048 + t)*64 + d];
  float4 r;
  r.x = (v.x - mu)*w + bb; r.y = (v.y - mu)*w + bb;
  r.z = (v.z - mu)*w + bb; r.w = (v.w - mu)*w + bb;
  *(float4*)&out[o] = r;
}

// current_kv = gamma*past_kv + mean_b K^T V  (reduce 128 partials)
__global__ __launch_bounds__(256) void k_ckb(const float* __restrict__ pkv, const uint16_t* __restrict__ ckp,
                                             float* __restrict__ out2){
  const int lin = blockIdx.x*256 + threadIdx.x;  // 16384
  const int i = lin*4;
  const int h = i >> 12, de = i & 4095;
  const float g = 1.0f - exp2f(-(float)(5 + h));
  float acc[4] = {0.0f, 0.0f, 0.0f, 0.0f};
  for (int b = 0; b < 4; ++b){
    const uint16_t* base = ckp + ((size_t)(b*16 + h)*32)*4096 + de;
    for (int c = 0; c < 32; ++c){
      #pragma unroll
      for (int u = 0; u < 4; ++u) acc[u] += bf2f(base[(size_t)c*4096 + u]);
    }
  }
  #pragma unroll
  for (int u = 0; u < 4; ++u)
    out2[i + u] = fmaf(g, pkv[i + u], 0.25f*acc[u]);
}

extern "C" void kernel_launch(void* const* d_in, const int* in_sizes, int n_in,
                              void* d_out, int out_size, void* d_ws, size_t ws_size,
                              hipStream_t stream){
  const float* x   = (const float*)d_in[0];
  const float* pkv = (const float*)d_in[1];
  const float* Wq  = (const float*)d_in[2];
  const float* Wk  = (const float*)d_in[3];
  const float* Wv  = (const float*)d_in[4];
  const float* gnw = (const float*)d_in[5];
  const float* gnb = (const float*)d_in[6];
  float* out  = (float*)d_out;
  float* out2 = out + 8388608;

  char* ws = (char*)d_ws;
  size_t off = 0;
  float*    stats = (float*)(ws + off);    off += 256;
  float2*   pb    = (float2*)(ws + off);   off += (size_t)8192*8;
  uint16_t* Xb    = (uint16_t*)(ws + off); off += (size_t)8388608*2;
  uint16_t* Wt    = (uint16_t*)(ws + off); off += (size_t)3145728*2;
  uint16_t* QKV   = (uint16_t*)(ws + off); off += (size_t)3*8388608*2;
  float*    ret   = (float*)(ws + off);    off += (size_t)8388608*4;
  uint16_t* U     = (uint16_t*)(ws + off); off += (size_t)8388608*2;
  uint16_t* S     = (uint16_t*)(ws + off); off += (size_t)8388608*2;
  uint16_t* CKp   = (uint16_t*)(ws + off); off += (size_t)8388608*2;
  float*    headv = (float*)(ws + off);    off += (size_t)131072*4;
  float*    tailv = (float*)(ws + off);    off += (size_t)131072*4;

  k_conv_x<<<8192, 256, 0, stream>>>(x, Xb);
  k_conv_w<<<dim3(16,16,3), 256, 0, stream>>>(Wq, Wk, Wv, Wt);
  k_gemm<<<dim3(128,48), 256, 0, stream>>>(Xb, Wt, QKV);
  k_r1<<<2048, 256, 0, stream>>>(QKV, ret, U, CKp);
  k_r2<<<64, 256, 0, stream>>>(U, S);
  k_r3<<<2048, 256, 0, stream>>>(QKV, S, ret);
  k_x1<<<2048, 256, 0, stream>>>(QKV, pkv, ret, headv);
  k_x2<<<16, 256, 0, stream>>>(headv, tailv);
  k_fin<<<dim3(2048,4), 256, 0, stream>>>(ret, tailv, pb);
  k_stats<<<4, 256, 0, stream>>>(pb, stats);
  k_norm<<<8192, 256, 0, stream>>>(ret, stats, gnw, gnb, out);
  k_ckb<<<64, 256, 0, stream>>>(pkv, CKp, out2);
}

// Round 3
// 284.896 us; speedup vs baseline: 2.4155x; 1.7119x over previous
//
#include <hip/hip_runtime.h>
#include <stdint.h>

typedef float v4f __attribute__((ext_vector_type(4)));
typedef short v8s __attribute__((ext_vector_type(8)));

#define SZ_BHTD 8388608   // B*H*T*DH
#define SZ_HTD  131072    // T*DH

#define GL2LDS(g, l) __builtin_amdgcn_global_load_lds( \
    (const __attribute__((address_space(1))) void*)(g), \
    (__attribute__((address_space(3))) void*)(l), 16, 0, 0)

__device__ __forceinline__ uint16_t f2bf(float f){
  uint32_t u = __float_as_uint(f);
  u += 0x7fffu + ((u >> 16) & 1u);
  return (uint16_t)(u >> 16);
}
__device__ __forceinline__ float bf2f(uint16_t v){
  return __uint_as_float(((uint32_t)v) << 16);
}

// x fp32 -> bf16 (4 elems/thread)
__global__ __launch_bounds__(256) void k_conv_x(const float* __restrict__ x, uint16_t* __restrict__ xb){
  int i = blockIdx.x*256 + threadIdx.x;
  const float4 v = ((const float4*)x)[i];
  ushort4 o; o.x = f2bf(v.x); o.y = f2bf(v.y); o.z = f2bf(v.z); o.w = f2bf(v.w);
  ((ushort4*)xb)[i] = o;
}

// Wq/Wk/Wv fp32 [1024][1024] -> Wt bf16 [3072][1024], Wt[n][k] = W[k][n]
__global__ __launch_bounds__(256) void k_conv_w(const float* __restrict__ Wq, const float* __restrict__ Wk,
                                                const float* __restrict__ Wv, uint16_t* __restrict__ wt){
  __shared__ float t[64][65];
  const float* W = blockIdx.z==0 ? Wq : (blockIdx.z==1 ? Wk : Wv);
  int n0 = blockIdx.x*64, k0 = blockIdx.y*64;
  for (int idx = threadIdx.x; idx < 4096; idx += 256){
    int r = idx >> 6, c = idx & 63;
    t[r][c] = W[(k0+r)*1024 + n0 + c];
  }
  __syncthreads();
  for (int idx = threadIdx.x; idx < 4096; idx += 256){
    int r = idx >> 6, c = idx & 63;   // r: local n, c: local k
    wt[(size_t)(blockIdx.z*1024 + n0 + r)*1024 + k0 + c] = f2bf(t[c][r]);
  }
}

// QKV = Xb @ Wt^T. m97 structure: 128x128 tile, BK=64, global_load_lds width 16.
// Out bf16 [3][B][H][T][DH].
__global__ __launch_bounds__(256) void k_gemm(const uint16_t* __restrict__ Xb, const uint16_t* __restrict__ Wt,
                                              uint16_t* __restrict__ qkv){
  __shared__ uint16_t As[128*64];   // row-major, 64-elem rows, NO pad (global_load_lds)
  __shared__ uint16_t Bs[128*64];
  const int tid = threadIdx.x;
  const int lane = tid & 63, w = tid >> 6;
  const int quad = lane >> 4, l16 = lane & 15;
  const int wm = (w >> 1)*64, wn = (w & 1)*64;
  const int bm = blockIdx.x, bn = blockIdx.y;
  v4f acc[4][4] = {};
  const uint16_t* Ag = Xb + (size_t)(bm*128)*1024;
  const uint16_t* Bg = Wt + (size_t)(bn*128)*1024;
  const int rA = (lane >> 3);          // 0..7 within 8-row chunk
  const int ce = (lane & 7)*8;         // 16B column chunk
  for (int k0 = 0; k0 < 1024; k0 += 64){
    #pragma unroll
    for (int j = 0; j < 4; ++j){
      const int cA = w*4 + j;          // chunk 0..15, covers rows [cA*8, cA*8+8)
      const int r = cA*8 + rA;
      GL2LDS(Ag + (size_t)r*1024 + k0 + ce, As + cA*512);
      GL2LDS(Bg + (size_t)r*1024 + k0 + ce, Bs + cA*512);
    }
    __syncthreads();
    #pragma unroll
    for (int kk = 0; kk < 64; kk += 32){
      v8s a[4], b[4];
      #pragma unroll
      for (int u = 0; u < 4; ++u) a[u] = *(v8s*)&As[(wm + u*16 + l16)*64 + kk + quad*8];
      #pragma unroll
      for (int u = 0; u < 4; ++u) b[u] = *(v8s*)&Bs[(wn + u*16 + l16)*64 + kk + quad*8];
      #pragma unroll
      for (int mi = 0; mi < 4; ++mi)
        #pragma unroll
        for (int ni = 0; ni < 4; ++ni)
          acc[mi][ni] = __builtin_amdgcn_mfma_f32_16x16x32_bf16(a[mi], b[ni], acc[mi][ni], 0, 0, 0);
    }
    __syncthreads();
  }
  #pragma unroll
  for (int mi = 0; mi < 4; ++mi){
    #pragma unroll
    for (int ni = 0; ni < 4; ++ni){
      int n = bn*128 + wn + ni*16 + l16;
      int which = n >> 10, cch = n & 1023;
      int hh = cch >> 6, dd = cch & 63;
      #pragma unroll
      for (int r = 0; r < 4; ++r){
        int m = bm*128 + wm + mi*16 + quad*4 + r;
        int b = m >> 11, t = m & 2047;
        qkv[(size_t)which*SZ_BHTD + (size_t)((b*16 + hh)*2048 + t)*64 + dd] = f2bf(acc[mi][ni][r]);
      }
    }
  }
}

// Per (b,h,chunk): UT[d][e]=sum_s g^{63-s}K[s][e]V[s][d]; CK[d][e]=sum_s K[s][d]V[s][e];
// head[e] = sum_j g^j pp[j][e] = qbar . pkv  with qbar[d]=sum_j g^j Q[j][d].  All MFMA except qbar/head.
__global__ __launch_bounds__(256) void k_pre(const uint16_t* __restrict__ qkv, const float* __restrict__ pkv,
                                             uint16_t* __restrict__ UT, uint16_t* __restrict__ ckp,
                                             float* __restrict__ headv){
  __shared__ uint16_t KTb[64*72];   // [d][s] = K[s][d]
  __shared__ uint16_t VTb[64*72];   // [e][s] = V[s][e]
  __shared__ uint16_t VTw[64*72];   // [d][s] = g^{63-s} V[s][d]
  __shared__ float tab[65];
  __shared__ float qbar[64];
  const int tid = threadIdx.x, blk = blockIdx.x;
  const int bh = blk >> 5, c = blk & 31, h = bh & 15;
  const int lane = tid & 63, w = tid >> 6;
  const int quad = lane >> 4, l16 = lane & 15;
  const float g = 1.0f - exp2f(-(float)(5 + h));
  if (tid <= 64) tab[tid] = powf(g, (float)tid);
  const uint16_t* Qg = qkv + (size_t)bh*SZ_HTD + c*4096;
  const uint16_t* Kg = Qg + SZ_BHTD;
  const uint16_t* Vg = Qg + 2*(size_t)SZ_BHTD;
  const float* Pg = pkv + h*4096;
  __syncthreads();
  #pragma unroll
  for (int it = 0; it < 16; ++it){
    int idx = it*256 + tid;            // idx = s*64 + d
    int s = idx >> 6, d = idx & 63;
    uint16_t kv = Kg[idx], vv = Vg[idx];
    KTb[d*72 + s] = kv;
    VTb[d*72 + s] = vv;
    VTw[d*72 + s] = f2bf(tab[63 - s]*bf2f(vv));
  }
  if (tid < 64){
    float acc = 0.f;
    for (int j = 0; j < 64; ++j) acc = fmaf(tab[j], bf2f(Qg[j*64 + tid]), acc);
    qbar[tid] = acc;
  }
  __syncthreads();
  const int ar = (w*16 + l16)*72 + quad*8;
  v8s aK0 = *(v8s*)&KTb[ar], aK1 = *(v8s*)&KTb[ar + 32];
  v8s aW0 = *(v8s*)&VTw[ar], aW1 = *(v8s*)&VTw[ar + 32];
  v4f accC[4] = {}, accU[4] = {};
  #pragma unroll
  for (int ni = 0; ni < 4; ++ni){
    const int br = (ni*16 + l16)*72 + quad*8;
    v8s bV0 = *(v8s*)&VTb[br], bV1 = *(v8s*)&VTb[br + 32];
    v8s bK0 = *(v8s*)&KTb[br], bK1 = *(v8s*)&KTb[br + 32];
    accC[ni] = __builtin_amdgcn_mfma_f32_16x16x32_bf16(aK0, bV0, accC[ni], 0, 0, 0);
    accC[ni] = __builtin_amdgcn_mfma_f32_16x16x32_bf16(aK1, bV1, accC[ni], 0, 0, 0);
    accU[ni] = __builtin_amdgcn_mfma_f32_16x16x32_bf16(aW0, bK0, accU[ni], 0, 0, 0);
    accU[ni] = __builtin_amdgcn_mfma_f32_16x16x32_bf16(aW1, bK1, accU[ni], 0, 0, 0);
  }
  const size_t ob = (size_t)blk*4096;
  #pragma unroll
  for (int ni = 0; ni < 4; ++ni){
    int e = ni*16 + l16;
    #pragma unroll
    for (int r = 0; r < 4; ++r){
      int d = w*16 + quad*4 + r;
      ckp[ob + d*64 + e] = f2bf(accC[ni][r]);
      UT[ob + d*64 + e]  = f2bf(accU[ni][r]);
    }
  }
  if (tid < 64){
    float acc = 0.f;
    for (int dd = 0; dd < 64; ++dd) acc = fmaf(qbar[dd], Pg[dd*64 + tid], acc);
    headv[(size_t)blk*64 + tid] = acc;
  }
}

// Forward chunk scan: S[c][idx] = state before chunk c (= A[e][d] at idx=d*64+e), coalesced UT reads.
__global__ __launch_bounds__(256) void k_r2(const uint16_t* __restrict__ UT, uint16_t* __restrict__ S){
  const int bh = blockIdx.x, part = blockIdx.y, h = bh & 15;
  const float g = 1.0f - exp2f(-(float)(5 + h));
  const float g64 = powf(g, 64.0f);
  const int off = part*1024 + threadIdx.x*4;
  float st0=0.f, st1=0.f, st2=0.f, st3=0.f;
  for (int c = 0; c < 32; ++c){
    const size_t base = ((size_t)bh*32 + c)*4096 + off;
    ushort4 u = *(const ushort4*)&UT[base];
    ushort4 o; o.x=f2bf(st0); o.y=f2bf(st1); o.z=f2bf(st2); o.w=f2bf(st3);
    *(ushort4*)&S[base] = o;
    st0 = fmaf(g64, st0, bf2f(u.x)); st1 = fmaf(g64, st1, bf2f(u.y));
    st2 = fmaf(g64, st2, bf2f(u.z)); st3 = fmaf(g64, st3, bf2f(u.w));
  }
}

// backward chunk scan: tail[c] = R_{c+1}, R_c = head[c] + g^64 * R_{c+1}
__global__ __launch_bounds__(256) void k_x2(const float* __restrict__ headv, float* __restrict__ tailv){
  const int lin = blockIdx.x*256 + threadIdx.x;   // 4096 = B*H*DH
  const int bh = lin >> 6, e = lin & 63, h = bh & 15;
  const float g = 1.0f - exp2f(-(float)(5 + h));
  const float g64 = powf(g, 64.0f);
  float R = 0.0f;
  for (int c = 31; c >= 0; --c){
    const size_t o = ((size_t)bh*32 + c)*64 + e;
    tailv[o] = R;
    R = fmaf(g64, R, headv[o]);
  }
}

// Fused main: per (b,h,c): P=QK^T (MFMA), pp=Q pkv^T (MFMA), inter=Q S^T (MFMA),
// intra=P' V (MFMA via LDS round-trip), cx = M pp^T (MFMA, M=upper-tri decay built in regs),
// ret = intra + g^{i+1} inter + cx + g^{64-i} tail; partial GroupNorm stats.
__global__ __launch_bounds__(256) void k_main(const uint16_t* __restrict__ qkv, const uint16_t* __restrict__ Sg_,
                                              const float* __restrict__ pkv, const float* __restrict__ tailv,
                                              float* __restrict__ ret, float2* __restrict__ pb){
  __shared__ uint16_t Qb[64*72];    // Q rows [i][d]
  __shared__ uint16_t Kb[64*72];    // K rows [j][d] -> P' rows [i][s]
  __shared__ uint16_t VTb[64*72];   // [d][s] = V[s][d]
  __shared__ uint16_t B2[64*72];    // [e][d] = pkv[d][e] -> ppT [e][j]
  __shared__ uint16_t Sb[64*72];    // S rows [d][e]
  __shared__ float tab[65];
  __shared__ float ps[8];
  const int tid = threadIdx.x, blk = blockIdx.x;
  const int bh = blk >> 5, c = blk & 31, h = bh & 15;
  const int lane = tid & 63, w = tid >> 6;
  const int quad = lane >> 4, l16 = lane & 15;
  const float g = 1.0f - exp2f(-(float)(5 + h));
  if (tid <= 64) tab[tid] = powf(g, (float)tid);
  const uint16_t* Qg = qkv + (size_t)bh*SZ_HTD + c*4096;
  const uint16_t* Kg = Qg + SZ_BHTD;
  const uint16_t* Vg = Qg + 2*(size_t)SZ_BHTD;
  const uint16_t* Sgp = Sg_ + (size_t)blk*4096;
  const float* Pg = pkv + h*4096;
  #pragma unroll
  for (int v = 0; v < 2; ++v){
    int idx = (tid*2 + v)*8;
    int r = idx >> 6, cc = idx & 63;
    *(uint4*)&Qb[r*72 + cc] = *(const uint4*)&Qg[idx];
    *(uint4*)&Kb[r*72 + cc] = *(const uint4*)&Kg[idx];
    *(uint4*)&Sb[r*72 + cc] = *(const uint4*)&Sgp[idx];
  }
  #pragma unroll
  for (int it = 0; it < 16; ++it){
    int idx = it*256 + tid;          // Vg: idx = s*64+d ; pkv: idx = d*64+e
    int r = idx >> 6, cc = idx & 63;
    VTb[cc*72 + r] = Vg[idx];        // VTb[d][s]
    B2[cc*72 + r] = f2bf(Pg[idx]);   // B2[e][d]
  }
  __syncthreads();
  const int ar = (w*16 + l16)*72 + quad*8;
  v8s aQ0 = *(v8s*)&Qb[ar], aQ1 = *(v8s*)&Qb[ar + 32];
  v4f accP[4] = {}, accPP[4] = {}, accIT[4] = {};
  #pragma unroll
  for (int ni = 0; ni < 4; ++ni){
    const int br = (ni*16 + l16)*72 + quad*8;
    v8s b0 = *(v8s*)&Kb[br], b1 = *(v8s*)&Kb[br + 32];
    accP[ni] = __builtin_amdgcn_mfma_f32_16x16x32_bf16(aQ0, b0, accP[ni], 0, 0, 0);
    accP[ni] = __builtin_amdgcn_mfma_f32_16x16x32_bf16(aQ1, b1, accP[ni], 0, 0, 0);
    v8s c0 = *(v8s*)&B2[br], c1 = *(v8s*)&B2[br + 32];
    accPP[ni] = __builtin_amdgcn_mfma_f32_16x16x32_bf16(aQ0, c0, accPP[ni], 0, 0, 0);
    accPP[ni] = __builtin_amdgcn_mfma_f32_16x16x32_bf16(aQ1, c1, accPP[ni], 0, 0, 0);
    v8s d0 = *(v8s*)&Sb[br], d1 = *(v8s*)&Sb[br + 32];
    accIT[ni] = __builtin_amdgcn_mfma_f32_16x16x32_bf16(aQ0, d0, accIT[ni], 0, 0, 0);
    accIT[ni] = __builtin_amdgcn_mfma_f32_16x16x32_bf16(aQ1, d1, accIT[ni], 0, 0, 0);
  }
  __syncthreads();   // all reads of Kb/B2 complete
  #pragma unroll
  for (int ni = 0; ni < 4; ++ni){
    #pragma unroll
    for (int r = 0; r < 4; ++r){
      int i = w*16 + quad*4 + r;     // row (time)
      int j = ni*16 + l16;           // col
      Kb[i*72 + j] = f2bf((i >= j) ? accP[ni][r]*tab[i - j] : 0.0f);   // P'
      B2[j*72 + i] = f2bf(accPP[ni][r]);                               // ppT[e][i]
    }
  }
  __syncthreads();
  v8s aP0 = *(v8s*)&Kb[ar], aP1 = *(v8s*)&Kb[ar + 32];
  v8s aM0, aM1;
  {
    int i = w*16 + l16;
    #pragma unroll
    for (int u = 0; u < 8; ++u){
      int j0 = quad*8 + u, j1 = 32 + quad*8 + u;
      aM0[u] = (short)f2bf((j0 >= i) ? tab[j0 - i] : 0.0f);
      aM1[u] = (short)f2bf((j1 >= i) ? tab[j1 - i] : 0.0f);
    }
  }
  v4f accI[4] = {}, accX[4] = {};
  #pragma unroll
  for (int ni = 0; ni < 4; ++ni){
    const int br = (ni*16 + l16)*72 + quad*8;
    v8s b0 = *(v8s*)&VTb[br], b1 = *(v8s*)&VTb[br + 32];
    accI[ni] = __builtin_amdgcn_mfma_f32_16x16x32_bf16(aP0, b0, accI[ni], 0, 0, 0);
    accI[ni] = __builtin_amdgcn_mfma_f32_16x16x32_bf16(aP1, b1, accI[ni], 0, 0, 0);
    v8s e0 = *(v8s*)&B2[br], e1 = *(v8s*)&B2[br + 32];
    accX[ni] = __builtin_amdgcn_mfma_f32_16x16x32_bf16(aM0, e0, accX[ni], 0, 0, 0);
    accX[ni] = __builtin_amdgcn_mfma_f32_16x16x32_bf16(aM1, e1, accX[ni], 0, 0, 0);
  }
  const size_t rbase = (size_t)bh*2048 + (size_t)c*64;
  float s1 = 0.f, s2 = 0.f;
  #pragma unroll
  for (int ni = 0; ni < 4; ++ni){
    int d = ni*16 + l16;
    float tl = tailv[(size_t)blk*64 + d];
    #pragma unroll
    for (int r = 0; r < 4; ++r){
      int i = w*16 + quad*4 + r;
      float v = accI[ni][r] + tab[i + 1]*accIT[ni][r] + accX[ni][r] + tab[64 - i]*tl;
      ret[(rbase + i)*64 + d] = v;
      s1 += v; s2 += v*v;
    }
  }
  #pragma unroll
  for (int off = 32; off > 0; off >>= 1){
    s1 += __shfl_down(s1, off);
    s2 += __shfl_down(s2, off);
  }
  if (lane == 0){ ps[w*2] = s1; ps[w*2+1] = s2; }
  __syncthreads();
  if (tid == 0){
    float2 o; o.x = ps[0] + ps[2] + ps[4] + ps[6];
    o.y = ps[1] + ps[3] + ps[5] + ps[7];
    pb[blk] = o;
  }
}

// reduce 512 per-block partials per batch -> stats
__global__ __launch_bounds__(256) void k_stats(const float2* __restrict__ pb, float* __restrict__ stats){
  __shared__ float ps[8];
  const int b = blockIdx.x;
  float s = 0.0f, s2 = 0.0f;
  for (int i = threadIdx.x; i < 512; i += 256){
    const float2 p = pb[(size_t)b*512 + i];
    s += p.x; s2 += p.y;
  }
  #pragma unroll
  for (int off = 32; off > 0; off >>= 1){
    s  += __shfl_down(s, off);
    s2 += __shfl_down(s2, off);
  }
  const int wv = threadIdx.x >> 6;
  if ((threadIdx.x & 63) == 0){ ps[wv*2] = s; ps[wv*2+1] = s2; }
  __syncthreads();
  if (threadIdx.x == 0){
    stats[b*2]   = ps[0] + ps[2] + ps[4] + ps[6];
    stats[b*2+1] = ps[1] + ps[3] + ps[5] + ps[7];
  }
}

// GroupNorm apply + layout to [B,T,NE]
__global__ __launch_bounds__(256) void k_norm(const float* __restrict__ ret, const float* __restrict__ stats,
                                              const float* __restrict__ gw, const float* __restrict__ gb,
                                              float* __restrict__ out){
  const int o = (blockIdx.x*256 + threadIdx.x)*4;
  const int b = o >> 21, t = (o >> 10) & 2047, cch = o & 1023;
  const int h = cch >> 6, d = cch & 63;
  const float inv = 1.0f/2097152.0f;
  const float mu = stats[b*2]*inv;
  const float var = stats[b*2+1]*inv - mu*mu;
  const float rs = rsqrtf(var + 1e-5f);
  const float w = gw[h]*rs, bb = gb[h];
  const float4 v = *(const float4*)&ret[((size_t)(b*16 + h)*2048 + t)*64 + d];
  float4 r;
  r.x = (v.x - mu)*w + bb; r.y = (v.y - mu)*w + bb;
  r.z = (v.z - mu)*w + bb; r.w = (v.w - mu)*w + bb;
  *(float4*)&out[o] = r;
}

// current_kv = gamma*past_kv + mean_b K^T V  (reduce 128 partials)
__global__ __launch_bounds__(256) void k_ckb(const float* __restrict__ pkv, const uint16_t* __restrict__ ckp,
                                             float* __restrict__ out2){
  const int lin = blockIdx.x*256 + threadIdx.x;  // 16384
  const int i = lin*4;
  const int h = i >> 12, de = i & 4095;
  const float g = 1.0f - exp2f(-(float)(5 + h));
  float acc[4] = {0.0f, 0.0f, 0.0f, 0.0f};
  for (int b = 0; b < 4; ++b){
    const uint16_t* base = ckp + ((size_t)(b*16 + h)*32)*4096 + de;
    for (int c = 0; c < 32; ++c){
      #pragma unroll
      for (int u = 0; u < 4; ++u) acc[u] += bf2f(base[(size_t)c*4096 + u]);
    }
  }
  #pragma unroll
  for (int u = 0; u < 4; ++u)
    out2[i + u] = fmaf(g, pkv[i + u], 0.25f*acc[u]);
}

extern "C" void kernel_launch(void* const* d_in, const int* in_sizes, int n_in,
                              void* d_out, int out_size, void* d_ws, size_t ws_size,
                              hipStream_t stream){
  const float* x   = (const float*)d_in[0];
  const float* pkv = (const float*)d_in[1];
  const float* Wq  = (const float*)d_in[2];
  const float* Wk  = (const float*)d_in[3];
  const float* Wv  = (const float*)d_in[4];
  const float* gnw = (const float*)d_in[5];
  const float* gnb = (const float*)d_in[6];
  float* out  = (float*)d_out;
  float* out2 = out + 8388608;

  char* ws = (char*)d_ws;
  size_t off = 0;
  float*    stats = (float*)(ws + off);    off += 256;
  float2*   pb    = (float2*)(ws + off);   off += (size_t)8192*8;
  uint16_t* Xb    = (uint16_t*)(ws + off); off += (size_t)8388608*2;
  uint16_t* Wt    = (uint16_t*)(ws + off); off += (size_t)3145728*2;
  uint16_t* QKV   = (uint16_t*)(ws + off); off += (size_t)3*8388608*2;
  float*    ret   = (float*)(ws + off);    off += (size_t)8388608*4;
  uint16_t* UT    = (uint16_t*)(ws + off); off += (size_t)8388608*2;
  uint16_t* S     = (uint16_t*)(ws + off); off += (size_t)8388608*2;
  uint16_t* CKp   = (uint16_t*)(ws + off); off += (size_t)8388608*2;
  float*    headv = (float*)(ws + off);    off += (size_t)131072*4;
  float*    tailv = (float*)(ws + off);    off += (size_t)131072*4;

  k_conv_x<<<8192, 256, 0, stream>>>(x, Xb);
  k_conv_w<<<dim3(16,16,3), 256, 0, stream>>>(Wq, Wk, Wv, Wt);
  k_gemm<<<dim3(64, 24), 256, 0, stream>>>(Xb, Wt, QKV);
  k_pre<<<2048, 256, 0, stream>>>(QKV, pkv, UT, CKp, headv);
  k_r2<<<dim3(64, 4), 256, 0, stream>>>(UT, S);
  k_x2<<<16, 256, 0, stream>>>(headv, tailv);
  k_main<<<2048, 256, 0, stream>>>(QKV, S, pkv, tailv, ret, pb);
  k_stats<<<4, 256, 0, stream>>>(pb, stats);
  k_norm<<<8192, 256, 0, stream>>>(ret, stats, gnw, gnb, out);
  k_ckb<<<64, 256, 0, stream>>>(pkv, CKp, out2);
}

// Round 4
// 254.708 us; speedup vs baseline: 2.7017x; 1.1185x over previous
//
#include <hip/hip_runtime.h>
#include <stdint.h>

typedef float v4f __attribute__((ext_vector_type(4)));
typedef short v8s __attribute__((ext_vector_type(8)));

#define SZ_BHTD 8388608   // B*H*T*DH
#define SZ_HTD  131072    // T*DH

#define GL2LDS(g, l) __builtin_amdgcn_global_load_lds( \
    (const __attribute__((address_space(1))) void*)(g), \
    (__attribute__((address_space(3))) void*)(l), 16, 0, 0)

__device__ __forceinline__ uint16_t f2bf(float f){
  uint32_t u = __float_as_uint(f);
  u += 0x7fffu + ((u >> 16) & 1u);
  return (uint16_t)(u >> 16);
}
__device__ __forceinline__ float bf2f(uint16_t v){
  return __uint_as_float(((uint32_t)v) << 16);
}

// Fused conversions: blocks [0,8192): x fp32->bf16; [8192,8960): W transpose->bf16
__global__ __launch_bounds__(256) void k_conv(const float* __restrict__ x,
                                              const float* __restrict__ Wq, const float* __restrict__ Wk,
                                              const float* __restrict__ Wv,
                                              uint16_t* __restrict__ xb, uint16_t* __restrict__ wt){
  if (blockIdx.x < 8192){
    int i = blockIdx.x*256 + threadIdx.x;
    const float4 v = ((const float4*)x)[i];
    ushort4 o; o.x = f2bf(v.x); o.y = f2bf(v.y); o.z = f2bf(v.z); o.w = f2bf(v.w);
    ((ushort4*)xb)[i] = o;
    return;
  }
  __shared__ float t[64][65];
  const int blk2 = blockIdx.x - 8192;          // [0,768)
  const int z = blk2 >> 8, y = (blk2 >> 4) & 15, xx = blk2 & 15;
  const float* W = z==0 ? Wq : (z==1 ? Wk : Wv);
  int n0 = xx*64, k0 = y*64;
  for (int idx = threadIdx.x; idx < 4096; idx += 256){
    int r = idx >> 6, c = idx & 63;
    t[r][c] = W[(k0+r)*1024 + n0 + c];
  }
  __syncthreads();
  for (int idx = threadIdx.x; idx < 4096; idx += 256){
    int r = idx >> 6, c = idx & 63;   // r: local n, c: local k
    wt[(size_t)(z*1024 + n0 + r)*1024 + k0 + c] = f2bf(t[c][r]);
  }
}

// QKV = Xb @ Wt^T. 128x128 tile, BK=64, global_load_lds width 16, XOR-swizzled LDS.
// LDS(r, c16) holds global(r, c16 ^ (r&7)); reader XORs chunk with (l16&7).
__global__ __launch_bounds__(256) void k_gemm(const uint16_t* __restrict__ Xb, const uint16_t* __restrict__ Wt,
                                              uint16_t* __restrict__ qkv){
  __shared__ uint16_t As[128*64];
  __shared__ uint16_t Bs[128*64];
  const int tid = threadIdx.x;
  const int lane = tid & 63, w = tid >> 6;
  const int quad = lane >> 4, l16 = lane & 15;
  const int wm = (w >> 1)*64, wn = (w & 1)*64;
  const int bm = blockIdx.x, bn = blockIdx.y;
  v4f acc[4][4] = {};
  const uint16_t* Ag = Xb + (size_t)(bm*128)*1024;
  const uint16_t* Bg = Wt + (size_t)(bn*128)*1024;
  const int rA = lane >> 3;                     // 0..7 row within 8-row chunk
  const int ce = (((lane & 7) ^ rA) * 8);       // swizzled 16B column chunk (elements)
  const int xr = l16 & 7;                       // reader-side XOR key
  for (int k0 = 0; k0 < 1024; k0 += 64){
    #pragma unroll
    for (int j = 0; j < 4; ++j){
      const int cA = w*4 + j;                   // covers rows [cA*8, cA*8+8)
      const int r = cA*8 + rA;
      GL2LDS(Ag + (size_t)r*1024 + k0 + ce, As + cA*512);
      GL2LDS(Bg + (size_t)r*1024 + k0 + ce, Bs + cA*512);
    }
    __syncthreads();
    #pragma unroll
    for (int kk = 0; kk < 64; kk += 32){
      const int ch = ((quad + (kk >> 3)) ^ xr) * 8;   // kk=0 -> quad, kk=32 -> quad+4, then XOR
      v8s a[4], b[4];
      #pragma unroll
      for (int u = 0; u < 4; ++u) a[u] = *(v8s*)&As[(wm + u*16 + l16)*64 + ch];
      #pragma unroll
      for (int u = 0; u < 4; ++u) b[u] = *(v8s*)&Bs[(wn + u*16 + l16)*64 + ch];
      #pragma unroll
      for (int mi = 0; mi < 4; ++mi)
        #pragma unroll
        for (int ni = 0; ni < 4; ++ni)
          acc[mi][ni] = __builtin_amdgcn_mfma_f32_16x16x32_bf16(a[mi], b[ni], acc[mi][ni], 0, 0, 0);
    }
    __syncthreads();
  }
  #pragma unroll
  for (int mi = 0; mi < 4; ++mi){
    #pragma unroll
    for (int ni = 0; ni < 4; ++ni){
      int n = bn*128 + wn + ni*16 + l16;
      int which = n >> 10, cch = n & 1023;
      int hh = cch >> 6, dd = cch & 63;
      #pragma unroll
      for (int r = 0; r < 4; ++r){
        int m = bm*128 + wm + mi*16 + quad*4 + r;
        int b = m >> 11, t = m & 2047;
        qkv[(size_t)which*SZ_BHTD + (size_t)((b*16 + hh)*2048 + t)*64 + dd] = f2bf(acc[mi][ni][r]);
      }
    }
  }
}

// Per (b,h,chunk): UT[d][e]=sum_s g^{63-s}K[s][e]V[s][d]; CK[d][e]=sum_s K[s][d]V[s][e];
// head[e] = qbar . pkv with qbar[d]=sum_j g^j Q[j][d].
__global__ __launch_bounds__(256) void k_pre(const uint16_t* __restrict__ qkv, const float* __restrict__ pkv,
                                             uint16_t* __restrict__ UT, uint16_t* __restrict__ ckp,
                                             float* __restrict__ headv){
  __shared__ uint16_t KTb[64*72];   // [d][s] = K[s][d]
  __shared__ uint16_t VTb[64*72];   // [e][s] = V[s][e]
  __shared__ uint16_t VTw[64*72];   // [d][s] = g^{63-s} V[s][d]
  __shared__ float tab[65];
  __shared__ float qbar[64];
  const int tid = threadIdx.x, blk = blockIdx.x;
  const int bh = blk >> 5, c = blk & 31, h = bh & 15;
  const int lane = tid & 63, w = tid >> 6;
  const int quad = lane >> 4, l16 = lane & 15;
  const float g = 1.0f - exp2f(-(float)(5 + h));
  if (tid <= 64) tab[tid] = powf(g, (float)tid);
  const uint16_t* Qg = qkv + (size_t)bh*SZ_HTD + c*4096;
  const uint16_t* Kg = Qg + SZ_BHTD;
  const uint16_t* Vg = Qg + 2*(size_t)SZ_BHTD;
  const float* Pg = pkv + h*4096;
  __syncthreads();
  #pragma unroll
  for (int it = 0; it < 16; ++it){
    int idx = it*256 + tid;            // idx = s*64 + d
    int s = idx >> 6, d = idx & 63;
    uint16_t kv = Kg[idx], vv = Vg[idx];
    KTb[d*72 + s] = kv;
    VTb[d*72 + s] = vv;
    VTw[d*72 + s] = f2bf(tab[63 - s]*bf2f(vv));
  }
  if (tid < 64){
    float acc = 0.f;
    for (int j = 0; j < 64; ++j) acc = fmaf(tab[j], bf2f(Qg[j*64 + tid]), acc);
    qbar[tid] = acc;
  }
  __syncthreads();
  const int ar = (w*16 + l16)*72 + quad*8;
  v8s aK0 = *(v8s*)&KTb[ar], aK1 = *(v8s*)&KTb[ar + 32];
  v8s aW0 = *(v8s*)&VTw[ar], aW1 = *(v8s*)&VTw[ar + 32];
  v4f accC[4] = {}, accU[4] = {};
  #pragma unroll
  for (int ni = 0; ni < 4; ++ni){
    const int br = (ni*16 + l16)*72 + quad*8;
    v8s bV0 = *(v8s*)&VTb[br], bV1 = *(v8s*)&VTb[br + 32];
    v8s bK0 = *(v8s*)&KTb[br], bK1 = *(v8s*)&KTb[br + 32];
    accC[ni] = __builtin_amdgcn_mfma_f32_16x16x32_bf16(aK0, bV0, accC[ni], 0, 0, 0);
    accC[ni] = __builtin_amdgcn_mfma_f32_16x16x32_bf16(aK1, bV1, accC[ni], 0, 0, 0);
    accU[ni] = __builtin_amdgcn_mfma_f32_16x16x32_bf16(aW0, bK0, accU[ni], 0, 0, 0);
    accU[ni] = __builtin_amdgcn_mfma_f32_16x16x32_bf16(aW1, bK1, accU[ni], 0, 0, 0);
  }
  const size_t ob = (size_t)blk*4096;
  #pragma unroll
  for (int ni = 0; ni < 4; ++ni){
    int e = ni*16 + l16;
    #pragma unroll
    for (int r = 0; r < 4; ++r){
      int d = w*16 + quad*4 + r;
      ckp[ob + d*64 + e] = f2bf(accC[ni][r]);
      UT[ob + d*64 + e]  = f2bf(accU[ni][r]);
    }
  }
  if (tid < 64){
    float acc = 0.f;
    for (int dd = 0; dd < 64; ++dd) acc = fmaf(qbar[dd], Pg[dd*64 + tid], acc);
    headv[(size_t)blk*64 + tid] = acc;
  }
}

// Merged scans. Blocks [0,256): forward state scan S; blocks [256,272): backward tail scan.
__global__ __launch_bounds__(256) void k_scan(const uint16_t* __restrict__ UT, uint16_t* __restrict__ S,
                                              const float* __restrict__ headv, float* __restrict__ tailv){
  if (blockIdx.x < 256){
    const int bh = blockIdx.x >> 2, part = blockIdx.x & 3, h = bh & 15;
    const float g = 1.0f - exp2f(-(float)(5 + h));
    const float g64 = powf(g, 64.0f);
    const int off = part*1024 + threadIdx.x*4;
    float st0=0.f, st1=0.f, st2=0.f, st3=0.f;
    for (int c = 0; c < 32; ++c){
      const size_t base = ((size_t)bh*32 + c)*4096 + off;
      ushort4 u = *(const ushort4*)&UT[base];
      ushort4 o; o.x=f2bf(st0); o.y=f2bf(st1); o.z=f2bf(st2); o.w=f2bf(st3);
      *(ushort4*)&S[base] = o;
      st0 = fmaf(g64, st0, bf2f(u.x)); st1 = fmaf(g64, st1, bf2f(u.y));
      st2 = fmaf(g64, st2, bf2f(u.z)); st3 = fmaf(g64, st3, bf2f(u.w));
    }
    return;
  }
  const int lin = (blockIdx.x - 256)*256 + threadIdx.x;   // 4096 = B*H*DH
  const int bh = lin >> 6, e = lin & 63, h = bh & 15;
  const float g = 1.0f - exp2f(-(float)(5 + h));
  const float g64 = powf(g, 64.0f);
  float R = 0.0f;
  for (int c = 31; c >= 0; --c){
    const size_t o = ((size_t)bh*32 + c)*64 + e;
    tailv[o] = R;
    R = fmaf(g64, R, headv[o]);
  }
}

// Fused main: P=QK^T, pp=Q pkv^T, inter=Q S^T, intra=P' V, cx = M pp^T (all MFMA);
// ret (bf16) = intra + g^{i+1} inter + cx + g^{64-i} tail; partial GroupNorm stats.
__global__ __launch_bounds__(256) void k_main(const uint16_t* __restrict__ qkv, const uint16_t* __restrict__ Sg_,
                                              const float* __restrict__ pkv, const float* __restrict__ tailv,
                                              uint16_t* __restrict__ ret, float2* __restrict__ pb){
  __shared__ uint16_t Qb[64*72];    // Q rows [i][d]
  __shared__ uint16_t Kb[64*72];    // K rows [j][d] -> P' rows [i][s]
  __shared__ uint16_t VTb[64*72];   // [d][s] = V[s][d]
  __shared__ uint16_t B2[64*72];    // [e][d] = pkv[d][e] -> ppT [e][j]
  __shared__ uint16_t Sb[64*72];    // S rows [d][e]
  __shared__ float tab[65];
  __shared__ float ps[8];
  const int tid = threadIdx.x, blk = blockIdx.x;
  const int bh = blk >> 5, c = blk & 31, h = bh & 15;
  const int lane = tid & 63, w = tid >> 6;
  const int quad = lane >> 4, l16 = lane & 15;
  const float g = 1.0f - exp2f(-(float)(5 + h));
  if (tid <= 64) tab[tid] = powf(g, (float)tid);
  const uint16_t* Qg = qkv + (size_t)bh*SZ_HTD + c*4096;
  const uint16_t* Kg = Qg + SZ_BHTD;
  const uint16_t* Vg = Qg + 2*(size_t)SZ_BHTD;
  const uint16_t* Sgp = Sg_ + (size_t)blk*4096;
  const float* Pg = pkv + h*4096;
  #pragma unroll
  for (int v = 0; v < 2; ++v){
    int idx = (tid*2 + v)*8;
    int r = idx >> 6, cc = idx & 63;
    *(uint4*)&Qb[r*72 + cc] = *(const uint4*)&Qg[idx];
    *(uint4*)&Kb[r*72 + cc] = *(const uint4*)&Kg[idx];
    *(uint4*)&Sb[r*72 + cc] = *(const uint4*)&Sgp[idx];
  }
  #pragma unroll
  for (int it = 0; it < 16; ++it){
    int idx = it*256 + tid;          // Vg: idx = s*64+d ; pkv: idx = d*64+e
    int r = idx >> 6, cc = idx & 63;
    VTb[cc*72 + r] = Vg[idx];        // VTb[d][s]
    B2[cc*72 + r] = f2bf(Pg[idx]);   // B2[e][d]
  }
  __syncthreads();
  const int ar = (w*16 + l16)*72 + quad*8;
  v8s aQ0 = *(v8s*)&Qb[ar], aQ1 = *(v8s*)&Qb[ar + 32];
  v4f accP[4] = {}, accPP[4] = {}, accIT[4] = {};
  #pragma unroll
  for (int ni = 0; ni < 4; ++ni){
    const int br = (ni*16 + l16)*72 + quad*8;
    v8s b0 = *(v8s*)&Kb[br], b1 = *(v8s*)&Kb[br + 32];
    accP[ni] = __builtin_amdgcn_mfma_f32_16x16x32_bf16(aQ0, b0, accP[ni], 0, 0, 0);
    accP[ni] = __builtin_amdgcn_mfma_f32_16x16x32_bf16(aQ1, b1, accP[ni], 0, 0, 0);
    v8s c0 = *(v8s*)&B2[br], c1 = *(v8s*)&B2[br + 32];
    accPP[ni] = __builtin_amdgcn_mfma_f32_16x16x32_bf16(aQ0, c0, accPP[ni], 0, 0, 0);
    accPP[ni] = __builtin_amdgcn_mfma_f32_16x16x32_bf16(aQ1, c1, accPP[ni], 0, 0, 0);
    v8s d0 = *(v8s*)&Sb[br], d1 = *(v8s*)&Sb[br + 32];
    accIT[ni] = __builtin_amdgcn_mfma_f32_16x16x32_bf16(aQ0, d0, accIT[ni], 0, 0, 0);
    accIT[ni] = __builtin_amdgcn_mfma_f32_16x16x32_bf16(aQ1, d1, accIT[ni], 0, 0, 0);
  }
  __syncthreads();   // all reads of Kb/B2 complete
  #pragma unroll
  for (int ni = 0; ni < 4; ++ni){
    #pragma unroll
    for (int r = 0; r < 4; ++r){
      int i = w*16 + quad*4 + r;     // row (time)
      int j = ni*16 + l16;           // col
      Kb[i*72 + j] = f2bf((i >= j) ? accP[ni][r]*tab[i - j] : 0.0f);   // P'
      B2[j*72 + i] = f2bf(accPP[ni][r]);                               // ppT[e][i]
    }
  }
  __syncthreads();
  v8s aP0 = *(v8s*)&Kb[ar], aP1 = *(v8s*)&Kb[ar + 32];
  v8s aM0, aM1;
  {
    int i = w*16 + l16;
    #pragma unroll
    for (int u = 0; u < 8; ++u){
      int j0 = quad*8 + u, j1 = 32 + quad*8 + u;
      aM0[u] = (short)f2bf((j0 >= i) ? tab[j0 - i] : 0.0f);
      aM1[u] = (short)f2bf((j1 >= i) ? tab[j1 - i] : 0.0f);
    }
  }
  v4f accI[4] = {}, accX[4] = {};
  #pragma unroll
  for (int ni = 0; ni < 4; ++ni){
    const int br = (ni*16 + l16)*72 + quad*8;
    v8s b0 = *(v8s*)&VTb[br], b1 = *(v8s*)&VTb[br + 32];
    accI[ni] = __builtin_amdgcn_mfma_f32_16x16x32_bf16(aP0, b0, accI[ni], 0, 0, 0);
    accI[ni] = __builtin_amdgcn_mfma_f32_16x16x32_bf16(aP1, b1, accI[ni], 0, 0, 0);
    v8s e0 = *(v8s*)&B2[br], e1 = *(v8s*)&B2[br + 32];
    accX[ni] = __builtin_amdgcn_mfma_f32_16x16x32_bf16(aM0, e0, accX[ni], 0, 0, 0);
    accX[ni] = __builtin_amdgcn_mfma_f32_16x16x32_bf16(aM1, e1, accX[ni], 0, 0, 0);
  }
  const size_t rbase = (size_t)bh*2048 + (size_t)c*64;
  float s1 = 0.f, s2 = 0.f;
  #pragma unroll
  for (int ni = 0; ni < 4; ++ni){
    int d = ni*16 + l16;
    float tl = tailv[(size_t)blk*64 + d];
    #pragma unroll
    for (int r = 0; r < 4; ++r){
      int i = w*16 + quad*4 + r;
      float v = accI[ni][r] + tab[i + 1]*accIT[ni][r] + accX[ni][r] + tab[64 - i]*tl;
      ret[(rbase + i)*64 + d] = f2bf(v);
      s1 += v; s2 += v*v;
    }
  }
  #pragma unroll
  for (int off = 32; off > 0; off >>= 1){
    s1 += __shfl_down(s1, off);
    s2 += __shfl_down(s2, off);
  }
  if (lane == 0){ ps[w*2] = s1; ps[w*2+1] = s2; }
  __syncthreads();
  if (tid == 0){
    float2 o; o.x = ps[0] + ps[2] + ps[4] + ps[6];
    o.y = ps[1] + ps[3] + ps[5] + ps[7];
    pb[blk] = o;
  }
}

// reduce 512 per-block partials per batch -> stats
__global__ __launch_bounds__(256) void k_stats(const float2* __restrict__ pb, float* __restrict__ stats){
  __shared__ float ps[8];
  const int b = blockIdx.x;
  float s = 0.0f, s2 = 0.0f;
  for (int i = threadIdx.x; i < 512; i += 256){
    const float2 p = pb[(size_t)b*512 + i];
    s += p.x; s2 += p.y;
  }
  #pragma unroll
  for (int off = 32; off > 0; off >>= 1){
    s  += __shfl_down(s, off);
    s2 += __shfl_down(s2, off);
  }
  const int wv = threadIdx.x >> 6;
  if ((threadIdx.x & 63) == 0){ ps[wv*2] = s; ps[wv*2+1] = s2; }
  __syncthreads();
  if (threadIdx.x == 0){
    stats[b*2]   = ps[0] + ps[2] + ps[4] + ps[6];
    stats[b*2+1] = ps[1] + ps[3] + ps[5] + ps[7];
  }
}

// GroupNorm apply + layout to [B,T,NE]
__global__ __launch_bounds__(256) void k_norm(const uint16_t* __restrict__ ret, const float* __restrict__ stats,
                                              const float* __restrict__ gw, const float* __restrict__ gb,
                                              float* __restrict__ out){
  const int o = (blockIdx.x*256 + threadIdx.x)*4;
  const int b = o >> 21, t = (o >> 10) & 2047, cch = o & 1023;
  const int h = cch >> 6, d = cch & 63;
  const float inv = 1.0f/2097152.0f;
  const float mu = stats[b*2]*inv;
  const float var = stats[b*2+1]*inv - mu*mu;
  const float rs = rsqrtf(var + 1e-5f);
  const float w = gw[h]*rs, bb = gb[h];
  const ushort4 v = *(const ushort4*)&ret[((size_t)(b*16 + h)*2048 + t)*64 + d];
  float4 r;
  r.x = (bf2f(v.x) - mu)*w + bb; r.y = (bf2f(v.y) - mu)*w + bb;
  r.z = (bf2f(v.z) - mu)*w + bb; r.w = (bf2f(v.w) - mu)*w + bb;
  *(float4*)&out[o] = r;
}

// current_kv = gamma*past_kv + mean_b K^T V  (reduce 128 partials)
__global__ __launch_bounds__(256) void k_ckb(const float* __restrict__ pkv, const uint16_t* __restrict__ ckp,
                                             float* __restrict__ out2){
  const int lin = blockIdx.x*256 + threadIdx.x;  // 16384
  const int i = lin*4;
  const int h = i >> 12, de = i & 4095;
  const float g = 1.0f - exp2f(-(float)(5 + h));
  float acc[4] = {0.0f, 0.0f, 0.0f, 0.0f};
  for (int b = 0; b < 4; ++b){
    const uint16_t* base = ckp + ((size_t)(b*16 + h)*32)*4096 + de;
    for (int c = 0; c < 32; ++c){
      #pragma unroll
      for (int u = 0; u < 4; ++u) acc[u] += bf2f(base[(size_t)c*4096 + u]);
    }
  }
  #pragma unroll
  for (int u = 0; u < 4; ++u)
    out2[i + u] = fmaf(g, pkv[i + u], 0.25f*acc[u]);
}

extern "C" void kernel_launch(void* const* d_in, const int* in_sizes, int n_in,
                              void* d_out, int out_size, void* d_ws, size_t ws_size,
                              hipStream_t stream){
  const float* x   = (const float*)d_in[0];
  const float* pkv = (const float*)d_in[1];
  const float* Wq  = (const float*)d_in[2];
  const float* Wk  = (const float*)d_in[3];
  const float* Wv  = (const float*)d_in[4];
  const float* gnw = (const float*)d_in[5];
  const float* gnb = (const float*)d_in[6];
  float* out  = (float*)d_out;
  float* out2 = out + 8388608;

  char* ws = (char*)d_ws;
  size_t off = 0;
  float*    stats = (float*)(ws + off);    off += 256;
  float2*   pb    = (float2*)(ws + off);   off += (size_t)8192*8;
  uint16_t* Xb    = (uint16_t*)(ws + off); off += (size_t)8388608*2;
  uint16_t* Wt    = (uint16_t*)(ws + off); off += (size_t)3145728*2;
  uint16_t* QKV   = (uint16_t*)(ws + off); off += (size_t)3*8388608*2;
  uint16_t* ret   = (uint16_t*)(ws + off); off += (size_t)8388608*2;
  uint16_t* UT    = (uint16_t*)(ws + off); off += (size_t)8388608*2;
  uint16_t* S     = (uint16_t*)(ws + off); off += (size_t)8388608*2;
  uint16_t* CKp   = (uint16_t*)(ws + off); off += (size_t)8388608*2;
  float*    headv = (float*)(ws + off);    off += (size_t)131072*4;
  float*    tailv = (float*)(ws + off);    off += (size_t)131072*4;

  k_conv<<<8960, 256, 0, stream>>>(x, Wq, Wk, Wv, Xb, Wt);
  k_gemm<<<dim3(64, 24), 256, 0, stream>>>(Xb, Wt, QKV);
  k_pre<<<2048, 256, 0, stream>>>(QKV, pkv, UT, CKp, headv);
  k_scan<<<272, 256, 0, stream>>>(UT, S, headv, tailv);
  k_main<<<2048, 256, 0, stream>>>(QKV, S, pkv, tailv, ret, pb);
  k_stats<<<4, 256, 0, stream>>>(pb, stats);
  k_norm<<<8192, 256, 0, stream>>>(ret, stats, gnw, gnb, out);
  k_ckb<<<64, 256, 0, stream>>>(pkv, CKp, out2);
}